// Round 9
// baseline (318.734 us; speedup 1.0000x reference)
//
#include <hip/hip_runtime.h>
#include <cmath>

#define NA 8192
#define DM 128
#define NW_ 256
#define WQ 32
#define HK 128
#define NH 4
#define DH 32
#define NL 3
#define TT 2048
#define FT_ 768
#define DD ((size_t)DM * DM)          // 16384
#define NM ((size_t)NA * DM)          // 1048576

typedef unsigned short u16;
typedef float f32x4 __attribute__((ext_vector_type(4)));
typedef short bhalf8 __attribute__((ext_vector_type(8)));

__device__ __forceinline__ float sigf(float x) { return 1.0f / (1.0f + expf(-x)); }

__device__ __forceinline__ u16 f2b(float f) {   // RNE f32 -> bf16
    unsigned u = __builtin_bit_cast(unsigned, f);
    return (u16)((u + 0x7fffu + ((u >> 16) & 1u)) >> 16);
}
__device__ __forceinline__ float b2f(u16 u) {
    return __builtin_bit_cast(float, (unsigned)u << 16);
}
__device__ __forceinline__ void unpk2(unsigned u, float& lo, float& hi) {
    lo = __builtin_bit_cast(float, u << 16);
    hi = __builtin_bit_cast(float, u & 0xffff0000u);
}

// =============== fused prep: weight convert+transpose | a=q+r@r2q, cn | counts ===============
// blocks [0,344): convert weight z=bx/8, col-chunk bx%8
// blocks [344,2392): ln_init rows
// blocks [2392,2424): count_tokens
// wt DD-offsets: 0-17 pre-weights  18 wq  21 wk  24 wv  27 wg  30 wo
// 33 wgate(2DD ea)  39 wlin  45 w2  51 wa2t(6DD)
__global__ __launch_bounds__(256) void prep(
    const float* __restrict__ s1w, const float* __restrict__ sh1w,
    const float* __restrict__ s2w, const float* __restrict__ sh2w,
    const float* __restrict__ wop, const float* __restrict__ wg2,
    const float* __restrict__ wq, const float* __restrict__ wk,
    const float* __restrict__ wv, const float* __restrict__ wg,
    const float* __restrict__ wo, const float* __restrict__ wgate,
    const float* __restrict__ wlin, const float* __restrict__ w2,
    const float* __restrict__ wa2t, u16* __restrict__ wt,
    const float* __restrict__ q_in, const float* __restrict__ r_in,
    const float* __restrict__ r2q, const float* __restrict__ c_in,
    float* __restrict__ a, u16* __restrict__ cnb, u16* __restrict__ cb,
    const int* __restrict__ tok, int* __restrict__ cnt)
{
    const int bx = blockIdx.x;
    if (bx < 344) {                       // ---- convert weights ----
        const int z = bx >> 3;
        const float* src; int K, N; size_t off;
        if (z < 33) {
            K = 128; N = 128; off = (size_t)z * DD;
            const int fam = z / 3, l = z - fam * 3;
            switch (fam) {
                case 0: src = s1w; break;  case 1: src = sh1w; break;
                case 2: src = s2w; break;  case 3: src = sh2w; break;
                case 4: src = wop; break;  case 5: src = wg2; break;
                case 6: src = wq; break;   case 7: src = wk; break;
                case 8: src = wv; break;   case 9: src = wg; break;
                default: src = wo; break;
            }
            src += (size_t)l * DD;
        } else if (z < 39) {
            K = 128; N = 256; off = 33 * DD + (size_t)(z - 33) * 2 * DD;
            src = (z < 36) ? wgate + (size_t)(z - 33) * 2 * DD
                           : wlin + (size_t)(z - 36) * 2 * DD;
        } else if (z < 42) {
            K = 256; N = 128; off = 45 * DD + (size_t)(z - 39) * 2 * DD;
            src = w2 + (size_t)(z - 39) * 2 * DD;
        } else {
            K = 128; N = 768; off = 51 * DD; src = wa2t;
        }
        const int kb = (K == 256) ? 8 : 7;
        const int nchunk = N >> 3;
        const int n0 = (bx & 7) * nchunk;
        u16* dst = wt + off;
        for (int f = threadIdx.x; f < (nchunk << kb); f += 256) {
            const int nl = f >> kb, k = f & (K - 1);
            dst[(size_t)(n0 + nl) * K + k] = f2b(src[(size_t)k * N + n0 + nl]);
        }
    } else if (bx < 2392) {               // ---- a = q + r@r2q ; cn/cb ----
        const int wave = threadIdx.x >> 6, lane = threadIdx.x & 63;
        const int row = ((bx - 344) << 2) + wave;
        const size_t base = (size_t)row * DM;
        const float r0 = r_in[row * 3 + 0], r1 = r_in[row * 3 + 1], r2 = r_in[row * 3 + 2];
        a[base + lane] = q_in[base + lane] + r0 * r2q[lane] + r1 * r2q[DM + lane]
                         + r2 * r2q[2 * DM + lane];
        a[base + lane + 64] = q_in[base + lane + 64] + r0 * r2q[lane + 64]
                              + r1 * r2q[DM + lane + 64] + r2 * r2q[2 * DM + lane + 64];
        float x0 = c_in[base + lane], x1 = c_in[base + lane + 64];
        cb[base + lane] = f2b(x0); cb[base + lane + 64] = f2b(x1);
        float s = x0 + x1, sq = x0 * x0 + x1 * x1;
#pragma unroll
        for (int off = 32; off >= 1; off >>= 1) {
            s += __shfl_xor(s, off, 64);
            sq += __shfl_xor(sq, off, 64);
        }
        const float m = s * (1.0f / 128.0f);
        const float inv = rsqrtf(sq * (1.0f / 128.0f) - m * m + 1e-5f);
        cnb[base + lane]      = f2b((x0 - m) * inv);
        cnb[base + lane + 64] = f2b((x1 - m) * inv);
    } else {                              // ---- token counts ----
        atomicAdd(&cnt[tok[(bx - 2392) * 256 + threadIdx.x]], 1);
    }
}

// =============== staging helpers (chunk-XOR swizzle, pitch 128 bf16) ===============
__device__ __forceinline__ void stage_tile(const u16* __restrict__ src, int row0,
                                           int ld, int k0, u16* dst)
{
#pragma unroll
    for (int i = 0; i < 4; ++i) {
        const int flat = (i << 8) + threadIdx.x;
        const int r = flat >> 4, s = flat & 15;
        const uint4 v = *reinterpret_cast<const uint4*>(
            src + (size_t)(row0 + r) * ld + k0 + (((s ^ (r & 7)) << 3)));
        *reinterpret_cast<uint4*>(dst + r * 128 + (s << 3)) = v;
    }
}

__device__ __forceinline__ void stage_tile128(const u16* __restrict__ src, int row0,
                                              int ld, int k0, u16* dst)
{
#pragma unroll
    for (int i = 0; i < 8; ++i) {
        const int flat = (i << 8) + threadIdx.x;
        const int r = flat >> 4, s = flat & 15;
        const uint4 v = *reinterpret_cast<const uint4*>(
            src + (size_t)(row0 + r) * ld + k0 + (((s ^ (r & 7)) << 3)));
        *reinterpret_cast<uint4*>(dst + r * 128 + (s << 3)) = v;
    }
}

// LN-fused A staging: src f32 [*][128], b = sp * LN(row) + sh (sp/sh bf16)
__device__ __forceinline__ void stage_ln(const float* __restrict__ a,
                                         const u16* __restrict__ sp,
                                         const u16* __restrict__ sh,
                                         int row0, u16* dst)
{
#pragma unroll
    for (int i = 0; i < 4; ++i) {
        const int flat = (i << 8) + threadIdx.x;
        const int r = flat >> 4, s = flat & 15;
        const int cs = s ^ (r & 7);
        const float* srcp = a + (size_t)(row0 + r) * 128 + (cs << 3);
        const float4 v0 = *reinterpret_cast<const float4*>(srcp);
        const float4 v1 = *reinterpret_cast<const float4*>(srcp + 4);
        float vv[8] = {v0.x, v0.y, v0.z, v0.w, v1.x, v1.y, v1.z, v1.w};
        float sum = 0.f, sq = 0.f;
#pragma unroll
        for (int e = 0; e < 8; ++e) { sum += vv[e]; sq += vv[e] * vv[e]; }
#pragma unroll
        for (int off = 8; off >= 1; off >>= 1) {    // reduce 16-lane row group
            sum += __shfl_xor(sum, off, 64);
            sq  += __shfl_xor(sq, off, 64);
        }
        const float m = sum * (1.0f / 128.0f);
        const float inv = rsqrtf(sq * (1.0f / 128.0f) - m * m + 1e-5f);
        const uint4 spv = *reinterpret_cast<const uint4*>(
            sp + (size_t)(row0 + r) * 128 + (cs << 3));
        const uint4 shv = *reinterpret_cast<const uint4*>(
            sh + (size_t)(row0 + r) * 128 + (cs << 3));
        float spf[8], shf[8];
        unpk2(spv.x, spf[0], spf[1]); unpk2(spv.y, spf[2], spf[3]);
        unpk2(spv.z, spf[4], spf[5]); unpk2(spv.w, spf[6], spf[7]);
        unpk2(shv.x, shf[0], shf[1]); unpk2(shv.y, shf[2], shf[3]);
        unpk2(shv.z, shf[4], shf[5]); unpk2(shv.w, shf[6], shf[7]);
        u16 outv[8];
#pragma unroll
        for (int e = 0; e < 8; ++e)
            outv[e] = f2b(spf[e] * (vv[e] - m) * inv + shf[e]);
        *reinterpret_cast<uint4*>(dst + r * 128 + (s << 3)) =
            *reinterpret_cast<uint4*>(outv);
    }
}

// =============== MFMA helpers ===============
__device__ __forceinline__ f32x4 mfma_bf16(bhalf8 a, bhalf8 b, f32x4 c) {
    return __builtin_amdgcn_mfma_f32_16x16x32_bf16(a, b, c, 0, 0, 0);
}

// 64x64-tile core (4 waves 2x2) — used by res_m / swiglu_m
__device__ __forceinline__ void mfma_tile128(const u16* As, const u16* Bs,
                                             int wm, int wn, int lr, int lk,
                                             f32x4 (&acc)[2][2])
{
#pragma unroll
    for (int kt = 0; kt < 4; ++kt) {
        const int j = (kt << 2) + lk;
        bhalf8 af[2], bf[2];
#pragma unroll
        for (int mf = 0; mf < 2; ++mf) {
            const int R = wm * 32 + mf * 16 + lr;
            af[mf] = *reinterpret_cast<const bhalf8*>(&As[R * 128 + ((j ^ (R & 7)) << 3)]);
        }
#pragma unroll
        for (int nf = 0; nf < 2; ++nf) {
            const int C = wn * 32 + nf * 16 + lr;
            bf[nf] = *reinterpret_cast<const bhalf8*>(&Bs[C * 128 + ((j ^ (C & 7)) << 3)]);
        }
#pragma unroll
        for (int mf = 0; mf < 2; ++mf)
#pragma unroll
            for (int nf = 0; nf < 2; ++nf)
                acc[mf][nf] = mfma_bf16(af[mf], bf[nf], acc[mf][nf]);
    }
}

template <int KTOT>
__device__ __forceinline__ void mcore(const u16* __restrict__ A,
                                      const u16* __restrict__ Wt,
                                      int m0, int n0, u16* As, u16* Bs,
                                      int wm, int wn, int lr, int lk,
                                      f32x4 (&acc)[2][2])
{
#pragma unroll
    for (int k0 = 0; k0 < KTOT; k0 += 128) {
        if (k0) __syncthreads();
        stage_tile(A, m0, KTOT, k0, As);
        stage_tile(Wt, n0, KTOT, k0, Bs);
        __syncthreads();
        mfma_tile128(As, Bs, wm, wn, lr, lk, acc);
    }
}

// 64x128-wide compute from staged As(64xK)/Bs(128xK): wave w -> rows [w*16,+16)
__device__ __forceinline__ void mfma_wide(const u16* As, const u16* Bs,
                                          int w, int lr, int lk, f32x4 (&acc)[8])
{
#pragma unroll
    for (int kt = 0; kt < 4; ++kt) {
        const int j = (kt << 2) + lk;
        const int R = w * 16 + lr;
        const bhalf8 af = *reinterpret_cast<const bhalf8*>(&As[R * 128 + ((j ^ (R & 7)) << 3)]);
#pragma unroll
        for (int nf = 0; nf < 8; ++nf) {
            const int C = nf * 16 + lr;
            const bhalf8 bf = *reinterpret_cast<const bhalf8*>(&Bs[C * 128 + ((j ^ (C & 7)) << 3)]);
            acc[nf] = mfma_bf16(af, bf, acc[nf]);
        }
    }
}

// epilogue helpers, 64x64 core: col = lane&15, row = (lane>>4)*4 + reg (m89-verified)
#define EPI_SETUP                                                         \
    const int lane = threadIdx.x & 63, w = threadIdx.x >> 6;              \
    const int wm = w >> 1, wn = w & 1, lr = lane & 15, lk = lane >> 4;    \
    const int m0 = blockIdx.x << 6, n0 = blockIdx.y << 6;
#define EPI_ROW (m0 + wm * 32 + mf * 16 + (lk << 2) + r)
#define EPI_COL (n0 + wn * 32 + nf * 16 + lr)
// wide (64x128) epilogue: row = m0 + w*16 + (lk<<2) + r ; col = nf*16 + lr
#define WEPI_SETUP                                                        \
    const int lane = threadIdx.x & 63, w = threadIdx.x >> 6;              \
    const int lr = lane & 15, lk = lane >> 4;                             \
    const int m0 = blockIdx.x << 6;
#define WEPI_ROW (m0 + w * 16 + (lk << 2) + r)

// =============== precompute: 18 loop-invariant GEMMs -> bf16 (64x128 tile) ===============
__global__ __launch_bounds__(256) void precompute_m(const u16* __restrict__ cnb,
                                                    const u16* __restrict__ cb,
                                                    const u16* __restrict__ wt,
                                                    const float* __restrict__ bop,
                                                    u16* __restrict__ pre)
{
    __shared__ u16 As[64 * 128], Bs[128 * 128];
    const int z = blockIdx.y;
    const u16* A = (z < 12) ? cnb : cb;
    const u16* Wt = wt + (size_t)z * DD;
    const bool sig = (z < 3) || (z >= 6 && z < 9) || (z >= 12);
    const float* bias = (z >= 12 && z < 15) ? bop + (size_t)(z - 12) * DM : nullptr;
    WEPI_SETUP
    f32x4 acc[8] = {};
    stage_tile(A, m0, 128, 0, As);
    stage_tile128(Wt, 0, 128, 0, Bs);
    __syncthreads();
    mfma_wide(As, Bs, w, lr, lk, acc);
    u16* out = pre + (size_t)z * NM;
#pragma unroll
    for (int nf = 0; nf < 8; ++nf)
#pragma unroll
        for (int r = 0; r < 4; ++r) {
            float v = acc[nf][r];
            const int col = nf * 16 + lr;
            if (bias) v += bias[col];
            if (sig) v = sigf(v);
            out[(size_t)WEPI_ROW * DM + col] = f2b(v);
        }
}

// =============== q/g/k/v projections (AdaLN fused, 64x128 tile) ===============
// qh is pre-scaled by 1/sqrt(DH) so attn logits skip the multiply.
__global__ __launch_bounds__(256) void qgkv_m(const float* __restrict__ a,
                                              const u16* __restrict__ sp,
                                              const u16* __restrict__ sh,
                                              const u16* __restrict__ wt, int l,
                                              const float* __restrict__ bq,
                                              u16* __restrict__ qh, u16* __restrict__ gb,
                                              u16* __restrict__ kf, u16* __restrict__ vf)
{
    __shared__ u16 As[64 * 128], Bs[128 * 128];
    const int z = blockIdx.y;
    const int wi = (z == 0 ? 18 : z == 1 ? 27 : z == 2 ? 21 : 24) + l;
    WEPI_SETUP
    f32x4 acc[8] = {};
    stage_ln(a, sp, sh, m0, As);
    stage_tile128(wt + (size_t)wi * DD, 0, 128, 0, Bs);
    __syncthreads();
    mfma_wide(As, Bs, w, lr, lk, acc);
    const float qscale = 0.17677669529663687f;   // 1/sqrt(32)
#pragma unroll
    for (int nf = 0; nf < 8; ++nf)
#pragma unroll
        for (int r = 0; r < 4; ++r) {
            const int col = nf * 16 + lr;
            const size_t off = (size_t)WEPI_ROW * DM + col;
            const float v = acc[nf][r];
            if (z == 0)      qh[off] = f2b((v + bq[col]) * qscale);
            else if (z == 1) gb[off] = f2b(sigf(v));
            else if (z == 2) kf[off] = f2b(v);
            else             vf[off] = f2b(v);
        }
}

// =============== MFMA attention: one block per (window, head) ===============
__global__ __launch_bounds__(256) void attn_m(const u16* __restrict__ qh,
                                              const u16* __restrict__ kf,
                                              const u16* __restrict__ vf,
                                              const int* __restrict__ kidx,
                                              const float* __restrict__ bias,
                                              const u16* __restrict__ gb,
                                              u16* __restrict__ ob)
{
    __shared__ __align__(16) unsigned char smem[47616];
    int*   idx_s = (int*)smem;                    // 512 B
    u16*   Qs = (u16*)(smem + 512);               // [32][40]
    u16*   Ks = (u16*)(smem + 3072);              // [128][40]
    u16*   Vt = (u16*)(smem + 13312);             // [32 dh][136]  V transposed
    u16*   Ps = (u16*)(smem + 22016);             // [32][136]  P bf16
    float* Ls = (float*)(smem + 30720);           // [32][132]  logits f32

    const int wdw = blockIdx.x, h = blockIdx.y;
    const int tid = threadIdx.x;
    const int lane = tid & 63, w = tid >> 6;
    const int lr = lane & 15, lk = lane >> 4;

    if (tid < 128) {
        idx_s[tid] = kidx[wdw * HK + tid];
        const int qi = tid >> 2, cs = (tid & 3) << 3;       // Q: 32x32
        const uint4 v = *reinterpret_cast<const uint4*>(
            qh + (size_t)(wdw * WQ + qi) * DM + h * DH + cs);
        *reinterpret_cast<uint4*>(&Qs[qi * 40 + cs]) = v;
    }
    __syncthreads();
#pragma unroll
    for (int i = 0; i < 2; ++i) {                           // gathered K,V: 128x32
        const int flat = (i << 8) + tid;
        const int kr = flat >> 2, cs = (flat & 3) << 3;
        const size_t src = (size_t)idx_s[kr] * DM + h * DH + cs;
        const uint4 kv = *reinterpret_cast<const uint4*>(kf + src);
        *reinterpret_cast<uint4*>(&Ks[kr * 40 + cs]) = kv;
        const uint4 vv = *reinterpret_cast<const uint4*>(vf + src);
        const u16* ve = reinterpret_cast<const u16*>(&vv);
#pragma unroll
        for (int e = 0; e < 8; ++e) Vt[(cs + e) * 136 + kr] = ve[e];  // transpose
    }
    __syncthreads();

    {   // QK^T (q pre-scaled): wave w covers keys [w*32, w*32+32)
        bhalf8 af[2];
        af[0] = *reinterpret_cast<const bhalf8*>(&Qs[lr * 40 + lk * 8]);
        af[1] = *reinterpret_cast<const bhalf8*>(&Qs[(16 + lr) * 40 + lk * 8]);
        f32x4 acc[2][2];
#pragma unroll
        for (int nf = 0; nf < 2; ++nf) {
            const int key = w * 32 + nf * 16 + lr;
            const bhalf8 bf = *reinterpret_cast<const bhalf8*>(&Ks[key * 40 + lk * 8]);
            f32x4 z = {0.f, 0.f, 0.f, 0.f};
            acc[0][nf] = mfma_bf16(af[0], bf, z);
            acc[1][nf] = mfma_bf16(af[1], bf, z);
        }
        const float* bb = bias + ((size_t)(wdw * NH + h) * WQ) * HK;
#pragma unroll
        for (int mf = 0; mf < 2; ++mf)
#pragma unroll
            for (int nf = 0; nf < 2; ++nf)
#pragma unroll
                for (int r = 0; r < 4; ++r) {
                    const int row = mf * 16 + (lk << 2) + r;
                    const int col = w * 32 + nf * 16 + lr;
                    Ls[row * 132 + col] = acc[mf][nf][r] + bb[row * HK + col];
                }
    }
    __syncthreads();

    {   // softmax: 8 threads/row, 16 cols each, in registers
        const int row = tid >> 3, sub = tid & 7;
        float x[16];
#pragma unroll
        for (int i = 0; i < 16; ++i) x[i] = Ls[row * 132 + sub * 16 + i];
        float mx = x[0];
#pragma unroll
        for (int i = 1; i < 16; ++i) mx = fmaxf(mx, x[i]);
#pragma unroll
        for (int off = 4; off >= 1; off >>= 1) mx = fmaxf(mx, __shfl_xor(mx, off, 64));
        float s = 0.f;
#pragma unroll
        for (int i = 0; i < 16; ++i) { x[i] = expf(x[i] - mx); s += x[i]; }
#pragma unroll
        for (int off = 4; off >= 1; off >>= 1) s += __shfl_xor(s, off, 64);
        const float inv = 1.0f / s;
        u16 pv[16];
#pragma unroll
        for (int i = 0; i < 16; ++i) pv[i] = f2b(x[i] * inv);
        *reinterpret_cast<uint4*>(&Ps[row * 136 + sub * 16]) =
            *reinterpret_cast<uint4*>(pv);
        *reinterpret_cast<uint4*>(&Ps[row * 136 + sub * 16 + 8]) =
            *reinterpret_cast<uint4*>(pv + 8);
    }
    __syncthreads();

    {   // PV: one 16x16 tile per wave; K=128 over 4 steps; gate + write
        const int mf = w >> 1, nf = w & 1;
        f32x4 acc = {0.f, 0.f, 0.f, 0.f};
#pragma unroll
        for (int ks = 0; ks < 4; ++ks) {
            const bhalf8 af = *reinterpret_cast<const bhalf8*>(
                &Ps[(mf * 16 + lr) * 136 + ks * 32 + lk * 8]);
            const bhalf8 bf = *reinterpret_cast<const bhalf8*>(
                &Vt[(nf * 16 + lr) * 136 + ks * 32 + lk * 8]);
            acc = mfma_bf16(af, bf, acc);
        }
#pragma unroll
        for (int r = 0; r < 4; ++r) {
            const int row = wdw * WQ + mf * 16 + (lk << 2) + r;
            const int col = h * DH + nf * 16 + lr;
            const size_t off = (size_t)row * DM + col;
            ob[off] = f2b(b2f(gb[off]) * acc[r]);
        }
    }
}

// =============== SwiGLU (AdaLN fused): h = silu(b@wga)*(b@wli) ===============
__global__ __launch_bounds__(256) void swiglu_m(const float* __restrict__ a,
                                                const u16* __restrict__ sp,
                                                const u16* __restrict__ sh,
                                                const u16* __restrict__ wga,
                                                const u16* __restrict__ wli,
                                                u16* __restrict__ h)
{
    __shared__ u16 As[64 * 128], B1[64 * 128], B2[64 * 128];
    EPI_SETUP
    f32x4 a1[2][2] = {}, a2[2][2] = {};
    stage_ln(a, sp, sh, m0, As);
    stage_tile(wga, n0, 128, 0, B1);
    stage_tile(wli, n0, 128, 0, B2);
    __syncthreads();
    mfma_tile128(As, B1, wm, wn, lr, lk, a1);
    mfma_tile128(As, B2, wm, wn, lr, lk, a2);
#pragma unroll
    for (int mf = 0; mf < 2; ++mf)
#pragma unroll
        for (int nf = 0; nf < 2; ++nf)
#pragma unroll
            for (int r = 0; r < 4; ++r) {
                const float x = a1[mf][nf][r];
                h[(size_t)EPI_ROW * 256 + EPI_COL] = f2b(x * sigf(x) * a2[mf][nf][r]);
            }
}

// =============== gated residual: a += gate*(Ab@Wt); abf = bf16(a) ===============
template <int KTOT>
__global__ __launch_bounds__(256) void res_m(const u16* __restrict__ Ab,
                                             const u16* __restrict__ Wt,
                                             const u16* __restrict__ gate,
                                             float* __restrict__ a,
                                             u16* __restrict__ abf)
{
    __shared__ u16 As[64 * 128], Bs[64 * 128];
    EPI_SETUP
    f32x4 acc[2][2] = {};
    mcore<KTOT>(Ab, Wt, m0, n0, As, Bs, wm, wn, lr, lk, acc);
#pragma unroll
    for (int mf = 0; mf < 2; ++mf)
#pragma unroll
        for (int nf = 0; nf < 2; ++nf)
#pragma unroll
            for (int r = 0; r < 4; ++r) {
                const size_t off = (size_t)EPI_ROW * DM + EPI_COL;
                const float v = a[off] + b2f(gate[off]) * acc[mf][nf][r];
                a[off] = v;
                abf[off] = f2b(v);
            }
}

// =============== final a2t: atomic relu mean-pool scatter (64x128 tile) ===============
__global__ __launch_bounds__(256) void a2t_m(const u16* __restrict__ Ab,
                                             const u16* __restrict__ Wt,
                                             const int* __restrict__ tokens,
                                             const int* __restrict__ counts,
                                             float* __restrict__ out)
{
    __shared__ u16 As[64 * 128], Bs[128 * 128];
    WEPI_SETUP
    const int n0 = blockIdx.y << 7;
    f32x4 acc[8] = {};
    stage_tile(Ab, m0, 128, 0, As);
    stage_tile128(Wt, n0, 128, 0, Bs);
    __syncthreads();
    mfma_wide(As, Bs, w, lr, lk, acc);
#pragma unroll
    for (int nf = 0; nf < 8; ++nf)
#pragma unroll
        for (int r = 0; r < 4; ++r) {
            const int row = WEPI_ROW;
            const int tok = tokens[row];
            const float sc = 1.0f / ((float)counts[tok] + 1e-6f);
            atomicAdd(out + (size_t)tok * FT_ + n0 + nf * 16 + lr,
                      fmaxf(acc[nf][r], 0.f) * sc);
        }
}

// =============== launcher ===============
extern "C" void kernel_launch(void* const* d_in, const int* in_sizes, int n_in,
                              void* d_out, int out_size, void* d_ws, size_t ws_size,
                              hipStream_t stream)
{
    (void)in_sizes; (void)n_in; (void)ws_size;
    const float* q_in  = (const float*)d_in[0];
    const float* c_in  = (const float*)d_in[1];
    const float* r_in  = (const float*)d_in[2];
    const float* bias  = (const float*)d_in[3];
    const int*   tok   = (const int*)d_in[4];
    const int*   kidx  = (const int*)d_in[5];
    const float* r2q   = (const float*)d_in[7];
    const float* s1w   = (const float*)d_in[8];
    const float* sh1w  = (const float*)d_in[9];
    const float* wq    = (const float*)d_in[10];
    const float* bq    = (const float*)d_in[11];
    const float* wk    = (const float*)d_in[12];
    const float* wv    = (const float*)d_in[13];
    const float* wg    = (const float*)d_in[14];
    const float* wo    = (const float*)d_in[15];
    const float* wop   = (const float*)d_in[16];
    const float* bop   = (const float*)d_in[17];
    const float* s2w   = (const float*)d_in[18];
    const float* sh2w  = (const float*)d_in[19];
    const float* wgate = (const float*)d_in[20];
    const float* wlin  = (const float*)d_in[21];
    const float* w2    = (const float*)d_in[22];
    const float* wg2   = (const float*)d_in[23];
    const float* wa2t  = (const float*)d_in[24];
    float* out = (float*)d_out;

    float* ws = (float*)d_ws;
    float* a_ = ws;                     // NM f32
    u16* u    = (u16*)(ws + NM);
    u16* pre_ = u;                      // 18 NM
    u16* qhb_ = u + 18 * NM;
    u16* gb_  = u + 19 * NM;
    u16* kfb_ = u + 20 * NM;
    u16* vfb_ = u + 21 * NM;
    u16* hb_  = u + 22 * NM;            // 2 NM
    u16* abf_ = u + 24 * NM;
    u16* cnb_ = u + 25 * NM;
    u16* cb_  = u + 26 * NM;
    u16* wt_  = u + 27 * NM;            // 57*DD < NM
    u16* ob_  = u + 28 * NM;
    int* cnt_ = (int*)(u + 29 * NM);

    hipMemsetAsync(d_out, 0, sizeof(float) * (size_t)out_size, stream);
    hipMemsetAsync(cnt_, 0, sizeof(int) * TT, stream);

    prep<<<2424, 256, 0, stream>>>(
        s1w, sh1w, s2w, sh2w, wop, wg2, wq, wk, wv, wg, wo, wgate, wlin, w2, wa2t, wt_,
        q_in, r_in, r2q, c_in, a_, cnb_, cb_, tok, cnt_);
    precompute_m<<<dim3(128, 18), 256, 0, stream>>>(cnb_, cb_, wt_, bop, pre_);

    for (int l = 0; l < NL; ++l) {
        const u16* S1p  = pre_ + (size_t)(0 + l) * NM;
        const u16* Sh1p = pre_ + (size_t)(3 + l) * NM;
        const u16* S2p  = pre_ + (size_t)(6 + l) * NM;
        const u16* Sh2p = pre_ + (size_t)(9 + l) * NM;
        const u16* Gop  = pre_ + (size_t)(12 + l) * NM;
        const u16* Gg2  = pre_ + (size_t)(15 + l) * NM;

        qgkv_m<<<dim3(128, 4), 256, 0, stream>>>(
            a_, S1p, Sh1p, wt_, l, bq + (size_t)l * DM, qhb_, gb_, kfb_, vfb_);
        attn_m<<<dim3(NW_, NH), 256, 0, stream>>>(qhb_, kfb_, vfb_, kidx, bias, gb_, ob_);
        res_m<128><<<dim3(128, 2), 256, 0, stream>>>(
            ob_, wt_ + (size_t)(30 + l) * DD, Gop, a_, abf_);
        swiglu_m<<<dim3(128, 4), 256, 0, stream>>>(
            a_, S2p, Sh2p, wt_ + (33 + 2 * (size_t)l) * DD,
            wt_ + (39 + 2 * (size_t)l) * DD, hb_);
        res_m<256><<<dim3(128, 2), 256, 0, stream>>>(
            hb_, wt_ + (45 + 2 * (size_t)l) * DD, Gg2, a_, abf_);
    }

    a2t_m<<<dim3(128, 6), 256, 0, stream>>>(abf_, wt_ + 51 * DD, tok, cnt_, out);
}

// Round 10
// 299.028 us; speedup vs baseline: 1.0659x; 1.0659x over previous
//
#include <hip/hip_runtime.h>
#include <cmath>

#define NA 8192
#define DM 128
#define NW_ 256
#define WQ 32
#define HK 128
#define NH 4
#define DH 32
#define NL 3
#define TT 2048
#define FT_ 768
#define DD ((size_t)DM * DM)          // 16384
#define NM ((size_t)NA * DM)          // 1048576

typedef unsigned short u16;
typedef float f32x4 __attribute__((ext_vector_type(4)));
typedef short bhalf8 __attribute__((ext_vector_type(8)));

__device__ __forceinline__ float sigf(float x) { return 1.0f / (1.0f + expf(-x)); }

__device__ __forceinline__ u16 f2b(float f) {   // RNE f32 -> bf16
    unsigned u = __builtin_bit_cast(unsigned, f);
    return (u16)((u + 0x7fffu + ((u >> 16) & 1u)) >> 16);
}
__device__ __forceinline__ float b2f(u16 u) {
    return __builtin_bit_cast(float, (unsigned)u << 16);
}
__device__ __forceinline__ void unpk2(unsigned u, float& lo, float& hi) {
    lo = __builtin_bit_cast(float, u << 16);
    hi = __builtin_bit_cast(float, u & 0xffff0000u);
}

// Swizzled bf16 global storage: element (row,col) of a [*][128] matrix lives at
// row*128 + ((col/8 ^ (row&7))*8) + col%8.  A 64xK tile is then a LINEAR copy
// into LDS whose chunk s holds original chunk s^(r&7) — exactly the layout the
// MFMA frag readers already expect.  [*][256]: same per 128-col group.
__device__ __forceinline__ int swz128(int row, int col) {
    return row * 128 + ((((col >> 3) ^ (row & 7)) & 15) << 3) + (col & 7);
}
__device__ __forceinline__ int swz256(int row, int col) {
    return row * 256 + (col & 128) + (((((col >> 3) & 15) ^ (row & 7))) << 3) + (col & 7);
}

// =============== async global->LDS staging (16B/lane, linear dest) ===============
__device__ __forceinline__ void gl16(const u16* g, u16* l) {
    __builtin_amdgcn_global_load_lds(
        (const __attribute__((address_space(1))) void*)g,
        (__attribute__((address_space(3))) void*)l, 16, 0, 0);
}

// 64-row tile, ld elements, k-offset k0; src pre-swizzled -> LDS linear
__device__ __forceinline__ void stage_gl64(const u16* __restrict__ src, int row0,
                                           int ld, int k0, u16* dst)
{
    const int tid = threadIdx.x;
#pragma unroll
    for (int i = 0; i < 4; ++i) {
        const int flat = (i << 8) + tid;
        const int r = flat >> 4, s = flat & 15;
        gl16(src + (size_t)(row0 + r) * ld + k0 + (s << 3),
             dst + (((i << 8) + (tid & ~63)) << 3));
    }
}

// 128-row tile
__device__ __forceinline__ void stage_gl128(const u16* __restrict__ src, int row0,
                                            int ld, int k0, u16* dst)
{
    const int tid = threadIdx.x;
#pragma unroll
    for (int i = 0; i < 8; ++i) {
        const int flat = (i << 8) + tid;
        const int r = flat >> 4, s = flat & 15;
        gl16(src + (size_t)(row0 + r) * ld + k0 + (s << 3),
             dst + (((i << 8) + (tid & ~63)) << 3));
    }
}

// =============== fused prep: weight convert+transpose | a=q+r@r2q, cn | counts ===============
// blocks [0,344): convert weight z=bx/8, col-chunk bx%8   (writes SWIZZLED)
// blocks [344,2392): ln_init rows                          (cnb/cb SWIZZLED)
// blocks [2392,2424): count_tokens
// wt DD-offsets: 0-17 pre-weights  18 wq  21 wk  24 wv  27 wg  30 wo
// 33 wgate(2DD ea)  39 wlin  45 w2  51 wa2t(6DD)
__global__ __launch_bounds__(256) void prep(
    const float* __restrict__ s1w, const float* __restrict__ sh1w,
    const float* __restrict__ s2w, const float* __restrict__ sh2w,
    const float* __restrict__ wop, const float* __restrict__ wg2,
    const float* __restrict__ wq, const float* __restrict__ wk,
    const float* __restrict__ wv, const float* __restrict__ wg,
    const float* __restrict__ wo, const float* __restrict__ wgate,
    const float* __restrict__ wlin, const float* __restrict__ w2,
    const float* __restrict__ wa2t, u16* __restrict__ wt,
    const float* __restrict__ q_in, const float* __restrict__ r_in,
    const float* __restrict__ r2q, const float* __restrict__ c_in,
    float* __restrict__ a, u16* __restrict__ cnb, u16* __restrict__ cb,
    const int* __restrict__ tok, int* __restrict__ cnt)
{
    const int bx = blockIdx.x;
    if (bx < 344) {                       // ---- convert weights (swizzled) ----
        const int z = bx >> 3;
        const float* src; int K, N; size_t off;
        if (z < 33) {
            K = 128; N = 128; off = (size_t)z * DD;
            const int fam = z / 3, l = z - fam * 3;
            switch (fam) {
                case 0: src = s1w; break;  case 1: src = sh1w; break;
                case 2: src = s2w; break;  case 3: src = sh2w; break;
                case 4: src = wop; break;  case 5: src = wg2; break;
                case 6: src = wq; break;   case 7: src = wk; break;
                case 8: src = wv; break;   case 9: src = wg; break;
                default: src = wo; break;
            }
            src += (size_t)l * DD;
        } else if (z < 39) {
            K = 128; N = 256; off = 33 * DD + (size_t)(z - 33) * 2 * DD;
            src = (z < 36) ? wgate + (size_t)(z - 33) * 2 * DD
                           : wlin + (size_t)(z - 36) * 2 * DD;
        } else if (z < 42) {
            K = 256; N = 128; off = 45 * DD + (size_t)(z - 39) * 2 * DD;
            src = w2 + (size_t)(z - 39) * 2 * DD;
        } else {
            K = 128; N = 768; off = 51 * DD; src = wa2t;
        }
        const int kb = (K == 256) ? 8 : 7;
        const int nchunk = N >> 3;
        const int n0 = (bx & 7) * nchunk;
        u16* dst = wt + off;
        for (int f = threadIdx.x; f < (nchunk << kb); f += 256) {
            const int nl = f >> kb, k = f & (K - 1);
            const int row = n0 + nl;
            int kk;
            if (K == 256)
                kk = (k & 128) | (((((k >> 3) & 15) ^ (row & 7)) << 3) | (k & 7));
            else
                kk = ((((k >> 3) ^ (row & 7)) & 15) << 3) | (k & 7);
            dst[(size_t)row * K + kk] = f2b(src[(size_t)k * N + row]);
        }
    } else if (bx < 2392) {               // ---- a = q + r@r2q ; cn/cb (swizzled) ----
        const int wave = threadIdx.x >> 6, lane = threadIdx.x & 63;
        const int row = ((bx - 344) << 2) + wave;
        const size_t base = (size_t)row * DM;
        const float r0 = r_in[row * 3 + 0], r1 = r_in[row * 3 + 1], r2 = r_in[row * 3 + 2];
        a[base + lane] = q_in[base + lane] + r0 * r2q[lane] + r1 * r2q[DM + lane]
                         + r2 * r2q[2 * DM + lane];
        a[base + lane + 64] = q_in[base + lane + 64] + r0 * r2q[lane + 64]
                              + r1 * r2q[DM + lane + 64] + r2 * r2q[2 * DM + lane + 64];
        float x0 = c_in[base + lane], x1 = c_in[base + lane + 64];
        cb[swz128(row, lane)] = f2b(x0);
        cb[swz128(row, lane + 64)] = f2b(x1);
        float s = x0 + x1, sq = x0 * x0 + x1 * x1;
#pragma unroll
        for (int off2 = 32; off2 >= 1; off2 >>= 1) {
            s += __shfl_xor(s, off2, 64);
            sq += __shfl_xor(sq, off2, 64);
        }
        const float m = s * (1.0f / 128.0f);
        const float inv = rsqrtf(sq * (1.0f / 128.0f) - m * m + 1e-5f);
        cnb[swz128(row, lane)]      = f2b((x0 - m) * inv);
        cnb[swz128(row, lane + 64)] = f2b((x1 - m) * inv);
    } else {                              // ---- token counts ----
        atomicAdd(&cnt[tok[(bx - 2392) * 256 + threadIdx.x]], 1);
    }
}

// LN-fused A staging: a f32 (linear), sp/sh bf16 SWIZZLED -> LDS swizzle layout
__device__ __forceinline__ void stage_ln(const float* __restrict__ a,
                                         const u16* __restrict__ sp,
                                         const u16* __restrict__ sh,
                                         int row0, u16* dst)
{
#pragma unroll
    for (int i = 0; i < 4; ++i) {
        const int flat = (i << 8) + threadIdx.x;
        const int r = flat >> 4, s = flat & 15;
        const int cs = s ^ (r & 7);
        const float* srcp = a + (size_t)(row0 + r) * 128 + (cs << 3);
        const float4 v0 = *reinterpret_cast<const float4*>(srcp);
        const float4 v1 = *reinterpret_cast<const float4*>(srcp + 4);
        float vv[8] = {v0.x, v0.y, v0.z, v0.w, v1.x, v1.y, v1.z, v1.w};
        float sum = 0.f, sq = 0.f;
#pragma unroll
        for (int e = 0; e < 8; ++e) { sum += vv[e]; sq += vv[e] * vv[e]; }
#pragma unroll
        for (int off = 8; off >= 1; off >>= 1) {    // reduce 16-lane row group
            sum += __shfl_xor(sum, off, 64);
            sq  += __shfl_xor(sq, off, 64);
        }
        const float m = sum * (1.0f / 128.0f);
        const float inv = rsqrtf(sq * (1.0f / 128.0f) - m * m + 1e-5f);
        // sp/sh stored swizzled: chunk s holds original chunk cs — linear read
        const uint4 spv = *reinterpret_cast<const uint4*>(
            sp + (size_t)(row0 + r) * 128 + (s << 3));
        const uint4 shv = *reinterpret_cast<const uint4*>(
            sh + (size_t)(row0 + r) * 128 + (s << 3));
        float spf[8], shf[8];
        unpk2(spv.x, spf[0], spf[1]); unpk2(spv.y, spf[2], spf[3]);
        unpk2(spv.z, spf[4], spf[5]); unpk2(spv.w, spf[6], spf[7]);
        unpk2(shv.x, shf[0], shf[1]); unpk2(shv.y, shf[2], shf[3]);
        unpk2(shv.z, shf[4], shf[5]); unpk2(shv.w, shf[6], shf[7]);
        u16 outv[8];
#pragma unroll
        for (int e = 0; e < 8; ++e)
            outv[e] = f2b(spf[e] * (vv[e] - m) * inv + shf[e]);
        *reinterpret_cast<uint4*>(dst + r * 128 + (s << 3)) =
            *reinterpret_cast<uint4*>(outv);
    }
}

// =============== MFMA helpers (frag readers unchanged) ===============
__device__ __forceinline__ f32x4 mfma_bf16(bhalf8 a, bhalf8 b, f32x4 c) {
    return __builtin_amdgcn_mfma_f32_16x16x32_bf16(a, b, c, 0, 0, 0);
}

__device__ __forceinline__ void mfma_tile128(const u16* As, const u16* Bs,
                                             int wm, int wn, int lr, int lk,
                                             f32x4 (&acc)[2][2])
{
#pragma unroll
    for (int kt = 0; kt < 4; ++kt) {
        const int j = (kt << 2) + lk;
        bhalf8 af[2], bf[2];
#pragma unroll
        for (int mf = 0; mf < 2; ++mf) {
            const int R = wm * 32 + mf * 16 + lr;
            af[mf] = *reinterpret_cast<const bhalf8*>(&As[R * 128 + ((j ^ (R & 7)) << 3)]);
        }
#pragma unroll
        for (int nf = 0; nf < 2; ++nf) {
            const int C = wn * 32 + nf * 16 + lr;
            bf[nf] = *reinterpret_cast<const bhalf8*>(&Bs[C * 128 + ((j ^ (C & 7)) << 3)]);
        }
#pragma unroll
        for (int mf = 0; mf < 2; ++mf)
#pragma unroll
            for (int nf = 0; nf < 2; ++nf)
                acc[mf][nf] = mfma_bf16(af[mf], bf[nf], acc[mf][nf]);
    }
}

template <int KTOT>
__device__ __forceinline__ void mcore(const u16* __restrict__ A,
                                      const u16* __restrict__ Wt,
                                      int m0, int n0, u16* As, u16* Bs,
                                      int wm, int wn, int lr, int lk,
                                      f32x4 (&acc)[2][2])
{
#pragma unroll
    for (int k0 = 0; k0 < KTOT; k0 += 128) {
        if (k0) __syncthreads();
        stage_gl64(A, m0, KTOT, k0, As);
        stage_gl64(Wt, n0, KTOT, k0, Bs);
        __syncthreads();
        mfma_tile128(As, Bs, wm, wn, lr, lk, acc);
    }
}

// 64x128-wide compute: wave w -> rows [w*16,+16)
__device__ __forceinline__ void mfma_wide(const u16* As, const u16* Bs,
                                          int w, int lr, int lk, f32x4 (&acc)[8])
{
#pragma unroll
    for (int kt = 0; kt < 4; ++kt) {
        const int j = (kt << 2) + lk;
        const int R = w * 16 + lr;
        const bhalf8 af = *reinterpret_cast<const bhalf8*>(&As[R * 128 + ((j ^ (R & 7)) << 3)]);
#pragma unroll
        for (int nf = 0; nf < 8; ++nf) {
            const int C = nf * 16 + lr;
            const bhalf8 bf = *reinterpret_cast<const bhalf8*>(&Bs[C * 128 + ((j ^ (C & 7)) << 3)]);
            acc[nf] = mfma_bf16(af, bf, acc[nf]);
        }
    }
}

// epilogue helpers: col = lane&15, row = (lane>>4)*4 + reg (m89-verified)
#define EPI_SETUP                                                         \
    const int lane = threadIdx.x & 63, w = threadIdx.x >> 6;              \
    const int wm = w >> 1, wn = w & 1, lr = lane & 15, lk = lane >> 4;    \
    const int m0 = blockIdx.x << 6, n0 = blockIdx.y << 6;
#define EPI_ROW (m0 + wm * 32 + mf * 16 + (lk << 2) + r)
#define EPI_COL (n0 + wn * 32 + nf * 16 + lr)
#define WEPI_SETUP                                                        \
    const int lane = threadIdx.x & 63, w = threadIdx.x >> 6;              \
    const int lr = lane & 15, lk = lane >> 4;                             \
    const int m0 = blockIdx.x << 6;
#define WEPI_ROW (m0 + w * 16 + (lk << 2) + r)

// =============== precompute: 18 loop-invariant GEMMs -> bf16 swizzled ===============
__global__ __launch_bounds__(256) void precompute_m(const u16* __restrict__ cnb,
                                                    const u16* __restrict__ cb,
                                                    const u16* __restrict__ wt,
                                                    const float* __restrict__ bop,
                                                    u16* __restrict__ pre)
{
    __shared__ u16 As[64 * 128], Bs[128 * 128];
    const int z = blockIdx.y;
    const u16* A = (z < 12) ? cnb : cb;
    const u16* Wt = wt + (size_t)z * DD;
    const bool sig = (z < 3) || (z >= 6 && z < 9) || (z >= 12);
    const float* bias = (z >= 12 && z < 15) ? bop + (size_t)(z - 12) * DM : nullptr;
    WEPI_SETUP
    f32x4 acc[8] = {};
    stage_gl64(A, m0, 128, 0, As);
    stage_gl128(Wt, 0, 128, 0, Bs);
    __syncthreads();
    mfma_wide(As, Bs, w, lr, lk, acc);
    u16* out = pre + (size_t)z * NM;
#pragma unroll
    for (int nf = 0; nf < 8; ++nf)
#pragma unroll
        for (int r = 0; r < 4; ++r) {
            float v = acc[nf][r];
            const int col = nf * 16 + lr;
            if (bias) v += bias[col];
            if (sig) v = sigf(v);
            out[swz128(WEPI_ROW, col)] = f2b(v);
        }
}

// =============== q/g/k/v projections (AdaLN fused, 64x128 tile) ===============
// qh pre-scaled by 1/sqrt(DH); outputs stored SWIZZLED
__global__ __launch_bounds__(256) void qgkv_m(const float* __restrict__ a,
                                              const u16* __restrict__ sp,
                                              const u16* __restrict__ sh,
                                              const u16* __restrict__ wt, int l,
                                              const float* __restrict__ bq,
                                              u16* __restrict__ qh, u16* __restrict__ gb,
                                              u16* __restrict__ kf, u16* __restrict__ vf)
{
    __shared__ u16 As[64 * 128], Bs[128 * 128];
    const int z = blockIdx.y;
    const int wi = (z == 0 ? 18 : z == 1 ? 27 : z == 2 ? 21 : 24) + l;
    WEPI_SETUP
    f32x4 acc[8] = {};
    stage_gl128(wt + (size_t)wi * DD, 0, 128, 0, Bs);
    stage_ln(a, sp, sh, m0, As);
    __syncthreads();
    mfma_wide(As, Bs, w, lr, lk, acc);
    const float qscale = 0.17677669529663687f;   // 1/sqrt(32)
#pragma unroll
    for (int nf = 0; nf < 8; ++nf)
#pragma unroll
        for (int r = 0; r < 4; ++r) {
            const int col = nf * 16 + lr;
            const int off = swz128(WEPI_ROW, col);
            const float v = acc[nf][r];
            if (z == 0)      qh[off] = f2b((v + bq[col]) * qscale);
            else if (z == 1) gb[off] = f2b(sigf(v));
            else if (z == 2) kf[off] = f2b(v);
            else             vf[off] = f2b(v);
        }
}

// =============== MFMA attention: one block per (window, head) ===============
// qh/kf/vf/gb swizzled (16B chunk = 1 swizzle unit -> XOR the chunk index)
__global__ __launch_bounds__(256) void attn_m(const u16* __restrict__ qh,
                                              const u16* __restrict__ kf,
                                              const u16* __restrict__ vf,
                                              const int* __restrict__ kidx,
                                              const float* __restrict__ bias,
                                              const u16* __restrict__ gb,
                                              u16* __restrict__ ob)
{
    __shared__ __align__(16) unsigned char smem[47616];
    int*   idx_s = (int*)smem;                    // 512 B
    u16*   Qs = (u16*)(smem + 512);               // [32][40]
    u16*   Ks = (u16*)(smem + 3072);              // [128][40]
    u16*   Vt = (u16*)(smem + 13312);             // [32 dh][136]  V transposed
    u16*   Ps = (u16*)(smem + 22016);             // [32][136]  P bf16
    float* Ls = (float*)(smem + 30720);           // [32][132]  logits f32

    const int wdw = blockIdx.x, h = blockIdx.y;
    const int tid = threadIdx.x;
    const int lane = tid & 63, w = tid >> 6;
    const int lr = lane & 15, lk = lane >> 4;

    if (tid < 128) {
        idx_s[tid] = kidx[wdw * HK + tid];
        const int qi = tid >> 2, cs = (tid & 3) << 3;       // Q: 32x32
        const int row = wdw * WQ + qi;
        const int cc = ((h * DH + cs) >> 3) ^ (row & 7);
        const uint4 v = *reinterpret_cast<const uint4*>(
            qh + (size_t)row * DM + (cc << 3));
        *reinterpret_cast<uint4*>(&Qs[qi * 40 + cs]) = v;
    }
    __syncthreads();
#pragma unroll
    for (int i = 0; i < 2; ++i) {                           // gathered K,V: 128x32
        const int flat = (i << 8) + tid;
        const int kr = flat >> 2, cs = (flat & 3) << 3;
        const int row = idx_s[kr];
        const int cc = ((h * DH + cs) >> 3) ^ (row & 7);
        const size_t src = (size_t)row * DM + (cc << 3);
        const uint4 kv = *reinterpret_cast<const uint4*>(kf + src);
        *reinterpret_cast<uint4*>(&Ks[kr * 40 + cs]) = kv;
        const uint4 vv = *reinterpret_cast<const uint4*>(vf + src);
        const u16* ve = reinterpret_cast<const u16*>(&vv);
#pragma unroll
        for (int e = 0; e < 8; ++e) Vt[(cs + e) * 136 + kr] = ve[e];  // transpose
    }
    __syncthreads();

    {   // QK^T (q pre-scaled): wave w covers keys [w*32, w*32+32)
        bhalf8 af[2];
        af[0] = *reinterpret_cast<const bhalf8*>(&Qs[lr * 40 + lk * 8]);
        af[1] = *reinterpret_cast<const bhalf8*>(&Qs[(16 + lr) * 40 + lk * 8]);
        f32x4 acc[2][2];
#pragma unroll
        for (int nf = 0; nf < 2; ++nf) {
            const int key = w * 32 + nf * 16 + lr;
            const bhalf8 bf = *reinterpret_cast<const bhalf8*>(&Ks[key * 40 + lk * 8]);
            f32x4 z = {0.f, 0.f, 0.f, 0.f};
            acc[0][nf] = mfma_bf16(af[0], bf, z);
            acc[1][nf] = mfma_bf16(af[1], bf, z);
        }
        const float* bb = bias + ((size_t)(wdw * NH + h) * WQ) * HK;
#pragma unroll
        for (int mf = 0; mf < 2; ++mf)
#pragma unroll
            for (int nf = 0; nf < 2; ++nf)
#pragma unroll
                for (int r = 0; r < 4; ++r) {
                    const int row = mf * 16 + (lk << 2) + r;
                    const int col = w * 32 + nf * 16 + lr;
                    Ls[row * 132 + col] = acc[mf][nf][r] + bb[row * HK + col];
                }
    }
    __syncthreads();

    {   // softmax: 8 threads/row, 16 cols each, in registers
        const int row = tid >> 3, sub = tid & 7;
        float x[16];
#pragma unroll
        for (int i = 0; i < 16; ++i) x[i] = Ls[row * 132 + sub * 16 + i];
        float mx = x[0];
#pragma unroll
        for (int i = 1; i < 16; ++i) mx = fmaxf(mx, x[i]);
#pragma unroll
        for (int off = 4; off >= 1; off >>= 1) mx = fmaxf(mx, __shfl_xor(mx, off, 64));
        float s = 0.f;
#pragma unroll
        for (int i = 0; i < 16; ++i) { x[i] = expf(x[i] - mx); s += x[i]; }
#pragma unroll
        for (int off = 4; off >= 1; off >>= 1) s += __shfl_xor(s, off, 64);
        const float inv = 1.0f / s;
        u16 pv[16];
#pragma unroll
        for (int i = 0; i < 16; ++i) pv[i] = f2b(x[i] * inv);
        *reinterpret_cast<uint4*>(&Ps[row * 136 + sub * 16]) =
            *reinterpret_cast<uint4*>(pv);
        *reinterpret_cast<uint4*>(&Ps[row * 136 + sub * 16 + 8]) =
            *reinterpret_cast<uint4*>(pv + 8);
    }
    __syncthreads();

    {   // PV: one 16x16 tile per wave; gate + write (ob swizzled)
        const int mf = w >> 1, nf = w & 1;
        f32x4 acc = {0.f, 0.f, 0.f, 0.f};
#pragma unroll
        for (int ks = 0; ks < 4; ++ks) {
            const bhalf8 af = *reinterpret_cast<const bhalf8*>(
                &Ps[(mf * 16 + lr) * 136 + ks * 32 + lk * 8]);
            const bhalf8 bf = *reinterpret_cast<const bhalf8*>(
                &Vt[(nf * 16 + lr) * 136 + ks * 32 + lk * 8]);
            acc = mfma_bf16(af, bf, acc);
        }
#pragma unroll
        for (int r = 0; r < 4; ++r) {
            const int row = wdw * WQ + mf * 16 + (lk << 2) + r;
            const int col = h * DH + nf * 16 + lr;
            const int off = swz128(row, col);
            ob[off] = f2b(b2f(gb[off]) * acc[r]);
        }
    }
}

// =============== SwiGLU (AdaLN fused): h = silu(b@wga)*(b@wli), h swizzled-256 ===============
__global__ __launch_bounds__(256) void swiglu_m(const float* __restrict__ a,
                                                const u16* __restrict__ sp,
                                                const u16* __restrict__ sh,
                                                const u16* __restrict__ wga,
                                                const u16* __restrict__ wli,
                                                u16* __restrict__ h)
{
    __shared__ u16 As[64 * 128], B1[64 * 128], B2[64 * 128];
    EPI_SETUP
    f32x4 a1[2][2] = {}, a2[2][2] = {};
    stage_gl64(wga, n0, 128, 0, B1);
    stage_gl64(wli, n0, 128, 0, B2);
    stage_ln(a, sp, sh, m0, As);
    __syncthreads();
    mfma_tile128(As, B1, wm, wn, lr, lk, a1);
    mfma_tile128(As, B2, wm, wn, lr, lk, a2);
#pragma unroll
    for (int mf = 0; mf < 2; ++mf)
#pragma unroll
        for (int nf = 0; nf < 2; ++nf)
#pragma unroll
            for (int r = 0; r < 4; ++r) {
                const float x = a1[mf][nf][r];
                h[swz256(EPI_ROW, EPI_COL)] = f2b(x * sigf(x) * a2[mf][nf][r]);
            }
}

// =============== gated residual: a += gate*(Ab@Wt); abf = bf16(a) swizzled ===============
template <int KTOT>
__global__ __launch_bounds__(256) void res_m(const u16* __restrict__ Ab,
                                             const u16* __restrict__ Wt,
                                             const u16* __restrict__ gate,
                                             float* __restrict__ a,
                                             u16* __restrict__ abf)
{
    __shared__ u16 As[64 * 128], Bs[64 * 128];
    EPI_SETUP
    f32x4 acc[2][2] = {};
    mcore<KTOT>(Ab, Wt, m0, n0, As, Bs, wm, wn, lr, lk, acc);
#pragma unroll
    for (int mf = 0; mf < 2; ++mf)
#pragma unroll
        for (int nf = 0; nf < 2; ++nf)
#pragma unroll
            for (int r = 0; r < 4; ++r) {
                const int row = EPI_ROW, col = EPI_COL;
                const size_t off = (size_t)row * DM + col;
                const int soff = swz128(row, col);
                const float v = a[off] + b2f(gate[soff]) * acc[mf][nf][r];
                a[off] = v;
                abf[soff] = f2b(v);
            }
}

// =============== final a2t: atomic relu mean-pool scatter (64x128 tile) ===============
__global__ __launch_bounds__(256) void a2t_m(const u16* __restrict__ Ab,
                                             const u16* __restrict__ Wt,
                                             const int* __restrict__ tokens,
                                             const int* __restrict__ counts,
                                             float* __restrict__ out)
{
    __shared__ u16 As[64 * 128], Bs[128 * 128];
    WEPI_SETUP
    const int n0 = blockIdx.y << 7;
    f32x4 acc[8] = {};
    stage_gl64(Ab, m0, 128, 0, As);
    stage_gl128(Wt, n0, 128, 0, Bs);
    __syncthreads();
    mfma_wide(As, Bs, w, lr, lk, acc);
#pragma unroll
    for (int nf = 0; nf < 8; ++nf)
#pragma unroll
        for (int r = 0; r < 4; ++r) {
            const int row = WEPI_ROW;
            const int tok = tokens[row];
            const float sc = 1.0f / ((float)counts[tok] + 1e-6f);
            atomicAdd(out + (size_t)tok * FT_ + n0 + nf * 16 + lr,
                      fmaxf(acc[nf][r], 0.f) * sc);
        }
}

// =============== launcher ===============
extern "C" void kernel_launch(void* const* d_in, const int* in_sizes, int n_in,
                              void* d_out, int out_size, void* d_ws, size_t ws_size,
                              hipStream_t stream)
{
    (void)in_sizes; (void)n_in; (void)ws_size;
    const float* q_in  = (const float*)d_in[0];
    const float* c_in  = (const float*)d_in[1];
    const float* r_in  = (const float*)d_in[2];
    const float* bias  = (const float*)d_in[3];
    const int*   tok   = (const int*)d_in[4];
    const int*   kidx  = (const int*)d_in[5];
    const float* r2q   = (const float*)d_in[7];
    const float* s1w   = (const float*)d_in[8];
    const float* sh1w  = (const float*)d_in[9];
    const float* wq    = (const float*)d_in[10];
    const float* bq    = (const float*)d_in[11];
    const float* wk    = (const float*)d_in[12];
    const float* wv    = (const float*)d_in[13];
    const float* wg    = (const float*)d_in[14];
    const float* wo    = (const float*)d_in[15];
    const float* wop   = (const float*)d_in[16];
    const float* bop   = (const float*)d_in[17];
    const float* s2w   = (const float*)d_in[18];
    const float* sh2w  = (const float*)d_in[19];
    const float* wgate = (const float*)d_in[20];
    const float* wlin  = (const float*)d_in[21];
    const float* w2    = (const float*)d_in[22];
    const float* wg2   = (const float*)d_in[23];
    const float* wa2t  = (const float*)d_in[24];
    float* out = (float*)d_out;

    float* ws = (float*)d_ws;
    float* a_ = ws;                     // NM f32
    u16* u    = (u16*)(ws + NM);
    u16* pre_ = u;                      // 18 NM
    u16* qhb_ = u + 18 * NM;
    u16* gb_  = u + 19 * NM;
    u16* kfb_ = u + 20 * NM;
    u16* vfb_ = u + 21 * NM;
    u16* hb_  = u + 22 * NM;            // 2 NM
    u16* abf_ = u + 24 * NM;
    u16* cnb_ = u + 25 * NM;
    u16* cb_  = u + 26 * NM;
    u16* wt_  = u + 27 * NM;            // 57*DD < NM
    u16* ob_  = u + 28 * NM;
    int* cnt_ = (int*)(u + 29 * NM);

    hipMemsetAsync(d_out, 0, sizeof(float) * (size_t)out_size, stream);
    hipMemsetAsync(cnt_, 0, sizeof(int) * TT, stream);

    prep<<<2424, 256, 0, stream>>>(
        s1w, sh1w, s2w, sh2w, wop, wg2, wq, wk, wv, wg, wo, wgate, wlin, w2, wa2t, wt_,
        q_in, r_in, r2q, c_in, a_, cnb_, cb_, tok, cnt_);
    precompute_m<<<dim3(128, 18), 256, 0, stream>>>(cnb_, cb_, wt_, bop, pre_);

    for (int l = 0; l < NL; ++l) {
        const u16* S1p  = pre_ + (size_t)(0 + l) * NM;
        const u16* Sh1p = pre_ + (size_t)(3 + l) * NM;
        const u16* S2p  = pre_ + (size_t)(6 + l) * NM;
        const u16* Sh2p = pre_ + (size_t)(9 + l) * NM;
        const u16* Gop  = pre_ + (size_t)(12 + l) * NM;
        const u16* Gg2  = pre_ + (size_t)(15 + l) * NM;

        qgkv_m<<<dim3(128, 4), 256, 0, stream>>>(
            a_, S1p, Sh1p, wt_, l, bq + (size_t)l * DM, qhb_, gb_, kfb_, vfb_);
        attn_m<<<dim3(NW_, NH), 256, 0, stream>>>(qhb_, kfb_, vfb_, kidx, bias, gb_, ob_);
        res_m<128><<<dim3(128, 2), 256, 0, stream>>>(
            ob_, wt_ + (size_t)(30 + l) * DD, Gop, a_, abf_);
        swiglu_m<<<dim3(128, 4), 256, 0, stream>>>(
            a_, S2p, Sh2p, wt_ + (33 + 2 * (size_t)l) * DD,
            wt_ + (39 + 2 * (size_t)l) * DD, hb_);
        res_m<256><<<dim3(128, 2), 256, 0, stream>>>(
            hb_, wt_ + (45 + 2 * (size_t)l) * DD, Gg2, a_, abf_);
    }

    a2t_m<<<dim3(128, 6), 256, 0, stream>>>(abf_, wt_ + 51 * DD, tok, cnt_, out);
}

// Round 11
// 292.505 us; speedup vs baseline: 1.0897x; 1.0223x over previous
//
#include <hip/hip_runtime.h>
#include <cmath>

#define NA 8192
#define DM 128
#define NW_ 256
#define WQ 32
#define HK 128
#define NH 4
#define DH 32
#define NL 3
#define TT 2048
#define FT_ 768
#define DD ((size_t)DM * DM)          // 16384
#define NM ((size_t)NA * DM)          // 1048576

typedef unsigned short u16;
typedef float f32x4 __attribute__((ext_vector_type(4)));
typedef short bhalf8 __attribute__((ext_vector_type(8)));

__device__ __forceinline__ float sigf(float x) { return 1.0f / (1.0f + expf(-x)); }

__device__ __forceinline__ u16 f2b(float f) {   // RNE f32 -> bf16
    unsigned u = __builtin_bit_cast(unsigned, f);
    return (u16)((u + 0x7fffu + ((u >> 16) & 1u)) >> 16);
}
__device__ __forceinline__ float b2f(u16 u) {
    return __builtin_bit_cast(float, (unsigned)u << 16);
}
__device__ __forceinline__ void unpk2(unsigned u, float& lo, float& hi) {
    lo = __builtin_bit_cast(float, u << 16);
    hi = __builtin_bit_cast(float, u & 0xffff0000u);
}

// Swizzled bf16 global storage: element (row,col) of a [*][128] matrix lives at
// row*128 + ((col/8 ^ (row&7))*8) + col%8.  A 64xK tile is then a LINEAR copy
// into LDS whose chunk s holds original chunk s^(r&7) — exactly the layout the
// MFMA frag readers already expect.  [*][256]: same per 128-col group.
__device__ __forceinline__ int swz128(int row, int col) {
    return row * 128 + ((((col >> 3) ^ (row & 7)) & 15) << 3) + (col & 7);
}
__device__ __forceinline__ int swz256(int row, int col) {
    return row * 256 + (col & 128) + (((((col >> 3) & 15) ^ (row & 7))) << 3) + (col & 7);
}

// =============== async global->LDS staging (16B/lane, linear dest) ===============
__device__ __forceinline__ void gl16(const u16* g, u16* l) {
    __builtin_amdgcn_global_load_lds(
        (const __attribute__((address_space(1))) void*)g,
        (__attribute__((address_space(3))) void*)l, 16, 0, 0);
}

// 64-row tile, ld elements, k-offset k0; src pre-swizzled -> LDS linear
__device__ __forceinline__ void stage_gl64(const u16* __restrict__ src, int row0,
                                           int ld, int k0, u16* dst)
{
    const int tid = threadIdx.x;
#pragma unroll
    for (int i = 0; i < 4; ++i) {
        const int flat = (i << 8) + tid;
        const int r = flat >> 4, s = flat & 15;
        gl16(src + (size_t)(row0 + r) * ld + k0 + (s << 3),
             dst + (((i << 8) + (tid & ~63)) << 3));
    }
}

// 128-row tile
__device__ __forceinline__ void stage_gl128(const u16* __restrict__ src, int row0,
                                            int ld, int k0, u16* dst)
{
    const int tid = threadIdx.x;
#pragma unroll
    for (int i = 0; i < 8; ++i) {
        const int flat = (i << 8) + tid;
        const int r = flat >> 4, s = flat & 15;
        gl16(src + (size_t)(row0 + r) * ld + k0 + (s << 3),
             dst + (((i << 8) + (tid & ~63)) << 3));
    }
}

// =============== fused prep: weight convert+transpose | a=q+r@r2q, cn | counts ===============
__global__ __launch_bounds__(256) void prep(
    const float* __restrict__ s1w, const float* __restrict__ sh1w,
    const float* __restrict__ s2w, const float* __restrict__ sh2w,
    const float* __restrict__ wop, const float* __restrict__ wg2,
    const float* __restrict__ wq, const float* __restrict__ wk,
    const float* __restrict__ wv, const float* __restrict__ wg,
    const float* __restrict__ wo, const float* __restrict__ wgate,
    const float* __restrict__ wlin, const float* __restrict__ w2,
    const float* __restrict__ wa2t, u16* __restrict__ wt,
    const float* __restrict__ q_in, const float* __restrict__ r_in,
    const float* __restrict__ r2q, const float* __restrict__ c_in,
    float* __restrict__ a, u16* __restrict__ cnb, u16* __restrict__ cb,
    const int* __restrict__ tok, int* __restrict__ cnt)
{
    const int bx = blockIdx.x;
    if (bx < 344) {                       // ---- convert weights (swizzled) ----
        const int z = bx >> 3;
        const float* src; int K, N; size_t off;
        if (z < 33) {
            K = 128; N = 128; off = (size_t)z * DD;
            const int fam = z / 3, l = z - fam * 3;
            switch (fam) {
                case 0: src = s1w; break;  case 1: src = sh1w; break;
                case 2: src = s2w; break;  case 3: src = sh2w; break;
                case 4: src = wop; break;  case 5: src = wg2; break;
                case 6: src = wq; break;   case 7: src = wk; break;
                case 8: src = wv; break;   case 9: src = wg; break;
                default: src = wo; break;
            }
            src += (size_t)l * DD;
        } else if (z < 39) {
            K = 128; N = 256; off = 33 * DD + (size_t)(z - 33) * 2 * DD;
            src = (z < 36) ? wgate + (size_t)(z - 33) * 2 * DD
                           : wlin + (size_t)(z - 36) * 2 * DD;
        } else if (z < 42) {
            K = 256; N = 128; off = 45 * DD + (size_t)(z - 39) * 2 * DD;
            src = w2 + (size_t)(z - 39) * 2 * DD;
        } else {
            K = 128; N = 768; off = 51 * DD; src = wa2t;
        }
        const int kb = (K == 256) ? 8 : 7;
        const int nchunk = N >> 3;
        const int n0 = (bx & 7) * nchunk;
        u16* dst = wt + off;
        for (int f = threadIdx.x; f < (nchunk << kb); f += 256) {
            const int nl = f >> kb, k = f & (K - 1);
            const int row = n0 + nl;
            int kk;
            if (K == 256)
                kk = (k & 128) | (((((k >> 3) & 15) ^ (row & 7)) << 3) | (k & 7));
            else
                kk = ((((k >> 3) ^ (row & 7)) & 15) << 3) | (k & 7);
            dst[(size_t)row * K + kk] = f2b(src[(size_t)k * N + row]);
        }
    } else if (bx < 2392) {               // ---- a = q + r@r2q ; cn/cb (swizzled) ----
        const int wave = threadIdx.x >> 6, lane = threadIdx.x & 63;
        const int row = ((bx - 344) << 2) + wave;
        const size_t base = (size_t)row * DM;
        const float r0 = r_in[row * 3 + 0], r1 = r_in[row * 3 + 1], r2 = r_in[row * 3 + 2];
        a[base + lane] = q_in[base + lane] + r0 * r2q[lane] + r1 * r2q[DM + lane]
                         + r2 * r2q[2 * DM + lane];
        a[base + lane + 64] = q_in[base + lane + 64] + r0 * r2q[lane + 64]
                              + r1 * r2q[DM + lane + 64] + r2 * r2q[2 * DM + lane + 64];
        float x0 = c_in[base + lane], x1 = c_in[base + lane + 64];
        cb[swz128(row, lane)] = f2b(x0);
        cb[swz128(row, lane + 64)] = f2b(x1);
        float s = x0 + x1, sq = x0 * x0 + x1 * x1;
#pragma unroll
        for (int off2 = 32; off2 >= 1; off2 >>= 1) {
            s += __shfl_xor(s, off2, 64);
            sq += __shfl_xor(sq, off2, 64);
        }
        const float m = s * (1.0f / 128.0f);
        const float inv = rsqrtf(sq * (1.0f / 128.0f) - m * m + 1e-5f);
        cnb[swz128(row, lane)]      = f2b((x0 - m) * inv);
        cnb[swz128(row, lane + 64)] = f2b((x1 - m) * inv);
    } else {                              // ---- token counts ----
        atomicAdd(&cnt[tok[(bx - 2392) * 256 + threadIdx.x]], 1);
    }
}

// LN-fused A staging: a f32 (linear), sp/sh bf16 SWIZZLED -> LDS swizzle layout
__device__ __forceinline__ void stage_ln(const float* __restrict__ a,
                                         const u16* __restrict__ sp,
                                         const u16* __restrict__ sh,
                                         int row0, u16* dst)
{
#pragma unroll
    for (int i = 0; i < 4; ++i) {
        const int flat = (i << 8) + threadIdx.x;
        const int r = flat >> 4, s = flat & 15;
        const int cs = s ^ (r & 7);
        const float* srcp = a + (size_t)(row0 + r) * 128 + (cs << 3);
        const float4 v0 = *reinterpret_cast<const float4*>(srcp);
        const float4 v1 = *reinterpret_cast<const float4*>(srcp + 4);
        float vv[8] = {v0.x, v0.y, v0.z, v0.w, v1.x, v1.y, v1.z, v1.w};
        float sum = 0.f, sq = 0.f;
#pragma unroll
        for (int e = 0; e < 8; ++e) { sum += vv[e]; sq += vv[e] * vv[e]; }
#pragma unroll
        for (int off = 8; off >= 1; off >>= 1) {    // reduce 16-lane row group
            sum += __shfl_xor(sum, off, 64);
            sq  += __shfl_xor(sq, off, 64);
        }
        const float m = sum * (1.0f / 128.0f);
        const float inv = rsqrtf(sq * (1.0f / 128.0f) - m * m + 1e-5f);
        const uint4 spv = *reinterpret_cast<const uint4*>(
            sp + (size_t)(row0 + r) * 128 + (s << 3));
        const uint4 shv = *reinterpret_cast<const uint4*>(
            sh + (size_t)(row0 + r) * 128 + (s << 3));
        float spf[8], shf[8];
        unpk2(spv.x, spf[0], spf[1]); unpk2(spv.y, spf[2], spf[3]);
        unpk2(spv.z, spf[4], spf[5]); unpk2(spv.w, spf[6], spf[7]);
        unpk2(shv.x, shf[0], shf[1]); unpk2(shv.y, shf[2], shf[3]);
        unpk2(shv.z, shf[4], shf[5]); unpk2(shv.w, shf[6], shf[7]);
        u16 outv[8];
#pragma unroll
        for (int e = 0; e < 8; ++e)
            outv[e] = f2b(spf[e] * (vv[e] - m) * inv + shf[e]);
        *reinterpret_cast<uint4*>(dst + r * 128 + (s << 3)) =
            *reinterpret_cast<uint4*>(outv);
    }
}

// =============== MFMA helpers ===============
__device__ __forceinline__ f32x4 mfma_bf16(bhalf8 a, bhalf8 b, f32x4 c) {
    return __builtin_amdgcn_mfma_f32_16x16x32_bf16(a, b, c, 0, 0, 0);
}

__device__ __forceinline__ void mfma_tile128(const u16* As, const u16* Bs,
                                             int wm, int wn, int lr, int lk,
                                             f32x4 (&acc)[2][2])
{
#pragma unroll
    for (int kt = 0; kt < 4; ++kt) {
        const int j = (kt << 2) + lk;
        bhalf8 af[2], bf[2];
#pragma unroll
        for (int mf = 0; mf < 2; ++mf) {
            const int R = wm * 32 + mf * 16 + lr;
            af[mf] = *reinterpret_cast<const bhalf8*>(&As[R * 128 + ((j ^ (R & 7)) << 3)]);
        }
#pragma unroll
        for (int nf = 0; nf < 2; ++nf) {
            const int C = wn * 32 + nf * 16 + lr;
            bf[nf] = *reinterpret_cast<const bhalf8*>(&Bs[C * 128 + ((j ^ (C & 7)) << 3)]);
        }
#pragma unroll
        for (int mf = 0; mf < 2; ++mf)
#pragma unroll
            for (int nf = 0; nf < 2; ++nf)
                acc[mf][nf] = mfma_bf16(af[mf], bf[nf], acc[mf][nf]);
    }
}

template <int KTOT>
__device__ __forceinline__ void mcore(const u16* __restrict__ A,
                                      const u16* __restrict__ Wt,
                                      int m0, int n0, u16* As, u16* Bs,
                                      int wm, int wn, int lr, int lk,
                                      f32x4 (&acc)[2][2])
{
#pragma unroll
    for (int k0 = 0; k0 < KTOT; k0 += 128) {
        if (k0) __syncthreads();
        stage_gl64(A, m0, KTOT, k0, As);
        stage_gl64(Wt, n0, KTOT, k0, Bs);
        __syncthreads();
        mfma_tile128(As, Bs, wm, wn, lr, lk, acc);
    }
}

// 64x128-wide compute: wave w -> rows [w*16,+16)
__device__ __forceinline__ void mfma_wide(const u16* As, const u16* Bs,
                                          int w, int lr, int lk, f32x4 (&acc)[8])
{
#pragma unroll
    for (int kt = 0; kt < 4; ++kt) {
        const int j = (kt << 2) + lk;
        const int R = w * 16 + lr;
        const bhalf8 af = *reinterpret_cast<const bhalf8*>(&As[R * 128 + ((j ^ (R & 7)) << 3)]);
#pragma unroll
        for (int nf = 0; nf < 8; ++nf) {
            const int C = nf * 16 + lr;
            const bhalf8 bf = *reinterpret_cast<const bhalf8*>(&Bs[C * 128 + ((j ^ (C & 7)) << 3)]);
            acc[nf] = mfma_bf16(af, bf, acc[nf]);
        }
    }
}

// epilogue helpers: col = lane&15, row = (lane>>4)*4 + reg (m89-verified)
#define EPI_SETUP                                                         \
    const int lane = threadIdx.x & 63, w = threadIdx.x >> 6;              \
    const int wm = w >> 1, wn = w & 1, lr = lane & 15, lk = lane >> 4;    \
    const int m0 = blockIdx.x << 6, n0 = blockIdx.y << 6;
#define EPI_ROW (m0 + wm * 32 + mf * 16 + (lk << 2) + r)
#define EPI_COL (n0 + wn * 32 + nf * 16 + lr)
#define WEPI_SETUP                                                        \
    const int lane = threadIdx.x & 63, w = threadIdx.x >> 6;              \
    const int lr = lane & 15, lk = lane >> 4;                             \
    const int m0 = blockIdx.x << 6;
#define WEPI_ROW (m0 + w * 16 + (lk << 2) + r)

// =============== precompute: 18 loop-invariant GEMMs -> bf16 swizzled ===============
__global__ __launch_bounds__(256) void precompute_m(const u16* __restrict__ cnb,
                                                    const u16* __restrict__ cb,
                                                    const u16* __restrict__ wt,
                                                    const float* __restrict__ bop,
                                                    u16* __restrict__ pre)
{
    __shared__ u16 As[64 * 128], Bs[128 * 128];
    const int z = blockIdx.y;
    const u16* A = (z < 12) ? cnb : cb;
    const u16* Wt = wt + (size_t)z * DD;
    const bool sig = (z < 3) || (z >= 6 && z < 9) || (z >= 12);
    const float* bias = (z >= 12 && z < 15) ? bop + (size_t)(z - 12) * DM : nullptr;
    WEPI_SETUP
    f32x4 acc[8] = {};
    stage_gl64(A, m0, 128, 0, As);
    stage_gl128(Wt, 0, 128, 0, Bs);
    __syncthreads();
    mfma_wide(As, Bs, w, lr, lk, acc);
    u16* out = pre + (size_t)z * NM;
#pragma unroll
    for (int nf = 0; nf < 8; ++nf)
#pragma unroll
        for (int r = 0; r < 4; ++r) {
            float v = acc[nf][r];
            const int col = nf * 16 + lr;
            if (bias) v += bias[col];
            if (sig) v = sigf(v);
            out[swz128(WEPI_ROW, col)] = f2b(v);
        }
}

// =============== q/g/k/v projections (AdaLN fused, 64x128 tile) ===============
__global__ __launch_bounds__(256) void qgkv_m(const float* __restrict__ a,
                                              const u16* __restrict__ sp,
                                              const u16* __restrict__ sh,
                                              const u16* __restrict__ wt, int l,
                                              const float* __restrict__ bq,
                                              u16* __restrict__ qh, u16* __restrict__ gb,
                                              u16* __restrict__ kf, u16* __restrict__ vf)
{
    __shared__ u16 As[64 * 128], Bs[128 * 128];
    const int z = blockIdx.y;
    const int wi = (z == 0 ? 18 : z == 1 ? 27 : z == 2 ? 21 : 24) + l;
    WEPI_SETUP
    f32x4 acc[8] = {};
    stage_gl128(wt + (size_t)wi * DD, 0, 128, 0, Bs);
    stage_ln(a, sp, sh, m0, As);
    __syncthreads();
    mfma_wide(As, Bs, w, lr, lk, acc);
    const float qscale = 0.17677669529663687f;   // 1/sqrt(32)
#pragma unroll
    for (int nf = 0; nf < 8; ++nf)
#pragma unroll
        for (int r = 0; r < 4; ++r) {
            const int col = nf * 16 + lr;
            const int off = swz128(WEPI_ROW, col);
            const float v = acc[nf][r];
            if (z == 0)      qh[off] = f2b((v + bq[col]) * qscale);
            else if (z == 1) gb[off] = f2b(sigf(v));
            else if (z == 2) kf[off] = f2b(v);
            else             vf[off] = f2b(v);
        }
}

// =============== fused attention + o@wo + gated residual ===============
// One block per window (256 thr); wave w = head h.  Q/K frags direct from
// swizzled global -> registers; in-register bias+softmax (lr-group shfl);
// P/Vt wave-private LDS (no barrier); O shared; wo aliases dead P region.
__global__ __launch_bounds__(256) void attn_owo(const u16* __restrict__ qh,
                                                const u16* __restrict__ kf,
                                                const u16* __restrict__ vf,
                                                const int* __restrict__ kidx,
                                                const float* __restrict__ bias,
                                                const u16* __restrict__ gb,
                                                const u16* __restrict__ wt_wo,
                                                const u16* __restrict__ gop,
                                                float* __restrict__ a)
{
    __shared__ __align__(16) unsigned char smem[78336];
    int* idx_s = (int*)smem;                      // 512 B
    u16* Pb    = (u16*)(smem + 512);              // 4 x [32][136] bf16 (per head)
    u16* Vtb   = (u16*)(smem + 35328);            // 4 x [32][136] V^T (per head)
    u16* Ol    = (u16*)(smem + 70144);            // [32][128] swizzled, shared
    u16* Wo    = (u16*)(smem + 512);              // phase2: [128][128] (alias P)

    const int wdw = blockIdx.x;
    const int tid = threadIdx.x;
    const int lane = tid & 63, h = tid >> 6;      // wave = head
    const int lr = lane & 15, lk = lane >> 4;
    u16* Ph  = Pb + h * 4352;
    u16* Vth = Vtb + h * 4352;

    if (tid < 128) idx_s[tid] = kidx[wdw * HK + tid];
    __syncthreads();

    // ---- V^T staging (own head slice, wave-private) ----
#pragma unroll
    for (int i = 0; i < 8; ++i) {
        const int flat = (i << 6) + lane;         // 0..511
        const int kr = flat >> 2, c = flat & 3;
        const int row = idx_s[kr];
        const int cc = ((h << 2) + c) ^ (row & 7);
        const uint4 vv = *reinterpret_cast<const uint4*>(vf + (size_t)row * DM + (cc << 3));
        const u16* ve = reinterpret_cast<const u16*>(&vv);
#pragma unroll
        for (int e = 0; e < 8; ++e) Vth[((c << 3) + e) * 136 + kr] = ve[e];
    }

    // ---- Q frags (global -> registers) ----
    bhalf8 af[2];
#pragma unroll
    for (int mf = 0; mf < 2; ++mf) {
        const int row = wdw * WQ + mf * 16 + lr;
        const int cc = ((h << 2) + lk) ^ (row & 7);
        af[mf] = *reinterpret_cast<const bhalf8*>(qh + (size_t)row * DM + (cc << 3));
    }

    // ---- logits: 32x128, K=32 -> one MFMA per 16x16 tile ----
    f32x4 acc[2][8];
#pragma unroll
    for (int nf = 0; nf < 8; ++nf) {
        const int key = nf * 16 + lr;
        const int row = idx_s[key];
        const int cc = ((h << 2) + lk) ^ (row & 7);
        const bhalf8 bf = *reinterpret_cast<const bhalf8*>(kf + (size_t)row * DM + (cc << 3));
        const f32x4 z = {0.f, 0.f, 0.f, 0.f};
        acc[0][nf] = mfma_bf16(af[0], bf, z);
        acc[1][nf] = mfma_bf16(af[1], bf, z);
    }

    // ---- bias + in-register softmax (row lives in lr-group x 8 regs) ----
    const float* bb = bias + (size_t)((wdw * NH + h) * WQ) * HK;
#pragma unroll
    for (int mf = 0; mf < 2; ++mf)
#pragma unroll
        for (int nf = 0; nf < 8; ++nf)
#pragma unroll
            for (int r = 0; r < 4; ++r)
                acc[mf][nf][r] += bb[(mf * 16 + (lk << 2) + r) * HK + nf * 16 + lr];
#pragma unroll
    for (int mf = 0; mf < 2; ++mf)
#pragma unroll
        for (int r = 0; r < 4; ++r) {
            float mx = acc[mf][0][r];
#pragma unroll
            for (int nf = 1; nf < 8; ++nf) mx = fmaxf(mx, acc[mf][nf][r]);
#pragma unroll
            for (int off = 8; off >= 1; off >>= 1) mx = fmaxf(mx, __shfl_xor(mx, off, 64));
            float s = 0.f;
#pragma unroll
            for (int nf = 0; nf < 8; ++nf) {
                acc[mf][nf][r] = expf(acc[mf][nf][r] - mx);
                s += acc[mf][nf][r];
            }
#pragma unroll
            for (int off = 8; off >= 1; off >>= 1) s += __shfl_xor(s, off, 64);
            const float inv = 1.0f / s;
            const int row = mf * 16 + (lk << 2) + r;
#pragma unroll
            for (int nf = 0; nf < 8; ++nf)
                Ph[row * 136 + nf * 16 + lr] = f2b(acc[mf][nf][r] * inv);
        }

    // ---- PV: 32x32 per head (wave-private P/Vt, no barrier needed) ----
    f32x4 po[2][2] = {};
#pragma unroll
    for (int ks = 0; ks < 4; ++ks) {
        bhalf8 pa[2], vb[2];
#pragma unroll
        for (int mf = 0; mf < 2; ++mf)
            pa[mf] = *reinterpret_cast<const bhalf8*>(&Ph[(mf * 16 + lr) * 136 + ks * 32 + lk * 8]);
#pragma unroll
        for (int nf = 0; nf < 2; ++nf)
            vb[nf] = *reinterpret_cast<const bhalf8*>(&Vth[(nf * 16 + lr) * 136 + ks * 32 + lk * 8]);
#pragma unroll
        for (int mf = 0; mf < 2; ++mf)
#pragma unroll
            for (int nf = 0; nf < 2; ++nf)
                po[mf][nf] = mfma_bf16(pa[mf], vb[nf], po[mf][nf]);
    }

    // ---- gate + write O (shared, swizzled rows) ----
#pragma unroll
    for (int mf = 0; mf < 2; ++mf)
#pragma unroll
        for (int nf = 0; nf < 2; ++nf)
#pragma unroll
            for (int r = 0; r < 4; ++r) {
                const int row = mf * 16 + (lk << 2) + r;      // window-local
                const int col = h * 32 + nf * 16 + lr;
                const float gv = b2f(gb[swz128(wdw * WQ + row, col)]);
                Ol[row * 128 + ((((col >> 3) ^ (row & 7)) & 15) << 3) + (col & 7)] =
                    f2b(gv * po[mf][nf][r]);
            }
    __syncthreads();                               // O ready; P/Vt dead

    // ---- stage wo (swizzled global) into alias region ----
#pragma unroll
    for (int i = 0; i < 8; ++i) {
        const int flat = (i << 8) + tid;
        const int rr = flat >> 4, ss = flat & 15;
        gl16(wt_wo + (size_t)rr * 128 + (ss << 3),
             Wo + (((i << 8) + (tid & ~63)) << 3));
        (void)ss;
    }
    __syncthreads();

    // ---- O @ wo^T + gated residual; wave w covers cols [h*32, h*32+32) ----
    f32x4 oc[2][2] = {};
#pragma unroll
    for (int ks = 0; ks < 4; ++ks) {
        const int j = (ks << 2) + lk;
        bhalf8 oa[2], wb2[2];
#pragma unroll
        for (int mf = 0; mf < 2; ++mf) {
            const int R = mf * 16 + lr;
            oa[mf] = *reinterpret_cast<const bhalf8*>(&Ol[R * 128 + ((j ^ (R & 7)) << 3)]);
        }
#pragma unroll
        for (int nf = 0; nf < 2; ++nf) {
            const int C = h * 32 + nf * 16 + lr;
            wb2[nf] = *reinterpret_cast<const bhalf8*>(&Wo[C * 128 + ((j ^ (C & 7)) << 3)]);
        }
#pragma unroll
        for (int mf = 0; mf < 2; ++mf)
#pragma unroll
            for (int nf = 0; nf < 2; ++nf)
                oc[mf][nf] = mfma_bf16(oa[mf], wb2[nf], oc[mf][nf]);
    }
#pragma unroll
    for (int mf = 0; mf < 2; ++mf)
#pragma unroll
        for (int nf = 0; nf < 2; ++nf)
#pragma unroll
            for (int r = 0; r < 4; ++r) {
                const int grow = wdw * WQ + mf * 16 + (lk << 2) + r;
                const int col = h * 32 + nf * 16 + lr;
                a[(size_t)grow * DM + col] +=
                    b2f(gop[swz128(grow, col)]) * oc[mf][nf][r];
            }
}

// =============== SwiGLU (AdaLN fused): h = silu(b@wga)*(b@wli), h swizzled-256 ===============
__global__ __launch_bounds__(256) void swiglu_m(const float* __restrict__ a,
                                                const u16* __restrict__ sp,
                                                const u16* __restrict__ sh,
                                                const u16* __restrict__ wga,
                                                const u16* __restrict__ wli,
                                                u16* __restrict__ h)
{
    __shared__ u16 As[64 * 128], B1[64 * 128], B2[64 * 128];
    EPI_SETUP
    f32x4 a1[2][2] = {}, a2[2][2] = {};
    stage_gl64(wga, n0, 128, 0, B1);
    stage_gl64(wli, n0, 128, 0, B2);
    stage_ln(a, sp, sh, m0, As);
    __syncthreads();
    mfma_tile128(As, B1, wm, wn, lr, lk, a1);
    mfma_tile128(As, B2, wm, wn, lr, lk, a2);
#pragma unroll
    for (int mf = 0; mf < 2; ++mf)
#pragma unroll
        for (int nf = 0; nf < 2; ++nf)
#pragma unroll
            for (int r = 0; r < 4; ++r) {
                const float x = a1[mf][nf][r];
                h[swz256(EPI_ROW, EPI_COL)] = f2b(x * sigf(x) * a2[mf][nf][r]);
            }
}

// =============== gated residual: a += gate*(Ab@Wt); abf = bf16(a) swizzled ===============
template <int KTOT>
__global__ __launch_bounds__(256) void res_m(const u16* __restrict__ Ab,
                                             const u16* __restrict__ Wt,
                                             const u16* __restrict__ gate,
                                             float* __restrict__ a,
                                             u16* __restrict__ abf)
{
    __shared__ u16 As[64 * 128], Bs[64 * 128];
    EPI_SETUP
    f32x4 acc[2][2] = {};
    mcore<KTOT>(Ab, Wt, m0, n0, As, Bs, wm, wn, lr, lk, acc);
#pragma unroll
    for (int mf = 0; mf < 2; ++mf)
#pragma unroll
        for (int nf = 0; nf < 2; ++nf)
#pragma unroll
            for (int r = 0; r < 4; ++r) {
                const int row = EPI_ROW, col = EPI_COL;
                const size_t off = (size_t)row * DM + col;
                const int soff = swz128(row, col);
                const float v = a[off] + b2f(gate[soff]) * acc[mf][nf][r];
                a[off] = v;
                abf[soff] = f2b(v);
            }
}

// =============== final a2t: atomic relu mean-pool scatter (64x128 tile) ===============
__global__ __launch_bounds__(256) void a2t_m(const u16* __restrict__ Ab,
                                             const u16* __restrict__ Wt,
                                             const int* __restrict__ tokens,
                                             const int* __restrict__ counts,
                                             float* __restrict__ out)
{
    __shared__ u16 As[64 * 128], Bs[128 * 128];
    WEPI_SETUP
    const int n0 = blockIdx.y << 7;
    f32x4 acc[8] = {};
    stage_gl64(Ab, m0, 128, 0, As);
    stage_gl128(Wt, n0, 128, 0, Bs);
    __syncthreads();
    mfma_wide(As, Bs, w, lr, lk, acc);
#pragma unroll
    for (int nf = 0; nf < 8; ++nf)
#pragma unroll
        for (int r = 0; r < 4; ++r) {
            const int row = WEPI_ROW;
            const int tok = tokens[row];
            const float sc = 1.0f / ((float)counts[tok] + 1e-6f);
            atomicAdd(out + (size_t)tok * FT_ + n0 + nf * 16 + lr,
                      fmaxf(acc[nf][r], 0.f) * sc);
        }
}

// =============== launcher ===============
extern "C" void kernel_launch(void* const* d_in, const int* in_sizes, int n_in,
                              void* d_out, int out_size, void* d_ws, size_t ws_size,
                              hipStream_t stream)
{
    (void)in_sizes; (void)n_in; (void)ws_size;
    const float* q_in  = (const float*)d_in[0];
    const float* c_in  = (const float*)d_in[1];
    const float* r_in  = (const float*)d_in[2];
    const float* bias  = (const float*)d_in[3];
    const int*   tok   = (const int*)d_in[4];
    const int*   kidx  = (const int*)d_in[5];
    const float* r2q   = (const float*)d_in[7];
    const float* s1w   = (const float*)d_in[8];
    const float* sh1w  = (const float*)d_in[9];
    const float* wq    = (const float*)d_in[10];
    const float* bq    = (const float*)d_in[11];
    const float* wk    = (const float*)d_in[12];
    const float* wv    = (const float*)d_in[13];
    const float* wg    = (const float*)d_in[14];
    const float* wo    = (const float*)d_in[15];
    const float* wop   = (const float*)d_in[16];
    const float* bop   = (const float*)d_in[17];
    const float* s2w   = (const float*)d_in[18];
    const float* sh2w  = (const float*)d_in[19];
    const float* wgate = (const float*)d_in[20];
    const float* wlin  = (const float*)d_in[21];
    const float* w2    = (const float*)d_in[22];
    const float* wg2   = (const float*)d_in[23];
    const float* wa2t  = (const float*)d_in[24];
    float* out = (float*)d_out;

    float* ws = (float*)d_ws;
    float* a_ = ws;                     // NM f32
    u16* u    = (u16*)(ws + NM);
    u16* pre_ = u;                      // 18 NM
    u16* qhb_ = u + 18 * NM;
    u16* gb_  = u + 19 * NM;
    u16* kfb_ = u + 20 * NM;
    u16* vfb_ = u + 21 * NM;
    u16* hb_  = u + 22 * NM;            // 2 NM
    u16* abf_ = u + 24 * NM;
    u16* cnb_ = u + 25 * NM;
    u16* cb_  = u + 26 * NM;
    u16* wt_  = u + 27 * NM;            // 57*DD < NM
    int* cnt_ = (int*)(u + 28 * NM);

    hipMemsetAsync(d_out, 0, sizeof(float) * (size_t)out_size, stream);
    hipMemsetAsync(cnt_, 0, sizeof(int) * TT, stream);

    prep<<<2424, 256, 0, stream>>>(
        s1w, sh1w, s2w, sh2w, wop, wg2, wq, wk, wv, wg, wo, wgate, wlin, w2, wa2t, wt_,
        q_in, r_in, r2q, c_in, a_, cnb_, cb_, tok, cnt_);
    precompute_m<<<dim3(128, 18), 256, 0, stream>>>(cnb_, cb_, wt_, bop, pre_);

    for (int l = 0; l < NL; ++l) {
        const u16* S1p  = pre_ + (size_t)(0 + l) * NM;
        const u16* Sh1p = pre_ + (size_t)(3 + l) * NM;
        const u16* S2p  = pre_ + (size_t)(6 + l) * NM;
        const u16* Sh2p = pre_ + (size_t)(9 + l) * NM;
        const u16* Gop  = pre_ + (size_t)(12 + l) * NM;
        const u16* Gg2  = pre_ + (size_t)(15 + l) * NM;

        qgkv_m<<<dim3(128, 4), 256, 0, stream>>>(
            a_, S1p, Sh1p, wt_, l, bq + (size_t)l * DM, qhb_, gb_, kfb_, vfb_);
        attn_owo<<<NW_, 256, 0, stream>>>(qhb_, kfb_, vfb_, kidx, bias, gb_,
                                          wt_ + (size_t)(30 + l) * DD, Gop, a_);
        swiglu_m<<<dim3(128, 4), 256, 0, stream>>>(
            a_, S2p, Sh2p, wt_ + (33 + 2 * (size_t)l) * DD,
            wt_ + (39 + 2 * (size_t)l) * DD, hb_);
        res_m<256><<<dim3(128, 2), 256, 0, stream>>>(
            hb_, wt_ + (45 + 2 * (size_t)l) * DD, Gg2, a_, abf_);
    }

    a2t_m<<<dim3(128, 6), 256, 0, stream>>>(abf_, wt_ + 51 * DD, tok, cnt_, out);
}